// Round 3
// baseline (1084.940 us; speedup 1.0000x reference)
//
#include <hip/hip_runtime.h>
#include <math.h>

// Problem constants: B=64, D=512, H=HID=512 -> M = B*D = 32768, K = N = 512.
#define MM 32768
#define KK 512
#define NN 512
#define BM 128
#define BN 128
#define BK 32
#define NT (KK / BK)   // 16 K-tiles

typedef float  f32x4  __attribute__((ext_vector_type(4)));
typedef __bf16 bf16x8 __attribute__((ext_vector_type(8)));
typedef unsigned short u16x8 __attribute__((ext_vector_type(8)));
typedef unsigned short u16x4 __attribute__((ext_vector_type(4)));

__device__ __forceinline__ unsigned short f2bf(float f) {
    union { float f; unsigned int u; } v; v.f = f;
    unsigned int r = v.u + 0x7fffu + ((v.u >> 16) & 1u);  // round-to-nearest-even
    return (unsigned short)(r >> 16);
}

__device__ __forceinline__ float bf2f(unsigned short h) {
    union { unsigned int u; float f; } v; v.u = ((unsigned int)h) << 16;
    return v.f;
}

__device__ __forceinline__ void gl_lds16(const void* g, void* l) {
    __builtin_amdgcn_global_load_lds((const __attribute__((address_space(1))) void*)g,
                                     (__attribute__((address_space(3))) void*)l,
                                     16, 0, 0);
}

// ---------------------------------------------------------------------------
// fsum = fea1+fea2+fea3+fea4, cast to bf16.  8 elements / thread.
// ---------------------------------------------------------------------------
__global__ __launch_bounds__(256)
void fsum_cast(const float* __restrict__ f1, const float* __restrict__ f2,
               const float* __restrict__ f3, const float* __restrict__ f4,
               unsigned short* __restrict__ out)
{
    const long i = ((long)blockIdx.x * 256 + threadIdx.x) * 8;
    f32x4 s0 = *(const f32x4*)(f1 + i);
    f32x4 s1 = *(const f32x4*)(f1 + i + 4);
    s0 += *(const f32x4*)(f2 + i);  s1 += *(const f32x4*)(f2 + i + 4);
    s0 += *(const f32x4*)(f3 + i);  s1 += *(const f32x4*)(f3 + i + 4);
    s0 += *(const f32x4*)(f4 + i);  s1 += *(const f32x4*)(f4 + i + 4);
    u16x8 o;
    o[0] = f2bf(s0[0]); o[1] = f2bf(s0[1]); o[2] = f2bf(s0[2]); o[3] = f2bf(s0[3]);
    o[4] = f2bf(s1[0]); o[5] = f2bf(s1[1]); o[6] = f2bf(s1[2]); o[7] = f2bf(s1[3]);
    *(u16x8*)(out + i) = o;
}

// ---------------------------------------------------------------------------
// Weight prep:
//   z = 0     : Wgb[k][t]   = 0.25 * W_gcn[k][t]          (bf16 cast, NO transpose)
//   z = 1..4  : W1T[n][t]   = sum_b W1_i[b*512 + t][n]    (transpose + concat collapse)
//   z = 5..8  : W2T[n][k]   = W2_i[k][n]                  (transpose)
// ---------------------------------------------------------------------------
struct WArgs {
    const float* src[9];
    unsigned short* dst[9];
};

__global__ __launch_bounds__(256)
void wprep(WArgs a)
{
    __shared__ float t[32][33];
    const int z  = blockIdx.z;
    const float* __restrict__ src = a.src[z];
    unsigned short* __restrict__ dst = a.dst[z];
    const int k0 = blockIdx.x * 32;
    const int n0 = blockIdx.y * 32;
    const int tx = threadIdx.x;
    if (z == 0) {
        for (int kk = threadIdx.y; kk < 32; kk += 8) {
            float v = src[(long)(k0 + kk) * 512 + n0 + tx];
            dst[(long)(k0 + kk) * 512 + n0 + tx] = f2bf(0.25f * v);
        }
        return;
    }
    for (int kk = threadIdx.y; kk < 32; kk += 8) {
        float v = src[(long)(k0 + kk) * 512 + n0 + tx];
        if (z >= 1 && z <= 4) {
            v += src[(long)(512  + k0 + kk) * 512 + n0 + tx];
            v += src[(long)(1024 + k0 + kk) * 512 + n0 + tx];
            v += src[(long)(1536 + k0 + kk) * 512 + n0 + tx];
        }
        t[kk][tx] = v;
    }
    __syncthreads();
    for (int nn = threadIdx.y; nn < 32; nn += 8) {
        dst[(long)(n0 + nn) * 512 + k0 + tx] = f2bf(t[tx][nn]);
    }
}

// ---------------------------------------------------------------------------
// bcomb_z[n] = sum_t b_gcn[t] * W1T_z[n][t] + b1_z[n]
// ---------------------------------------------------------------------------
struct BArgs {
    const unsigned short* w1t[4];
    const float* b1[4];
    float* out[4];
};

__global__ __launch_bounds__(256)
void bprep(const float* __restrict__ bg, BArgs a)
{
    __shared__ float bgs[512];
    const int z = blockIdx.x;
    const int tid = threadIdx.x;
    bgs[tid]       = bg[tid];
    bgs[tid + 256] = bg[tid + 256];
    __syncthreads();
    const unsigned short* __restrict__ w = a.w1t[z];
    for (int n = tid; n < 512; n += 256) {
        float acc = 0.0f;
        const unsigned short* row = w + (long)n * 512;
        #pragma unroll 4
        for (int t = 0; t < 512; t += 8) {
            u16x8 wv = *(const u16x8*)(row + t);
            #pragma unroll
            for (int jj = 0; jj < 8; ++jj) acc += bgs[t + jj] * bf2f(wv[jj]);
        }
        a.out[z][n] = acc + a.b1[z][n];
    }
}

// ---------------------------------------------------------------------------
// Small GEMM (kept only for MODE 3: WcombT compose, 512x512x512).
// 3-deep counted-vmcnt pipeline, K-seg XOR swizzle (verified r2).
// ---------------------------------------------------------------------------
struct GArgs {
    const unsigned short* A[4];
    const unsigned short* Bt[4];
    const float* bias[4];
    const float* fea[4];
    void* out[4];
};

__device__ __forceinline__ void stage4(const unsigned short* gb, unsigned short* lb, int r) {
    #pragma unroll
    for (int c = 0; c < 4; ++c)
        gl_lds16(gb + (long)(c * 16 + r) * KK, lb + c * 16 * BK);
}

template<int MODE>
__global__ __launch_bounds__(256)
void gemm_ep(GArgs a)
{
    __shared__ __attribute__((aligned(16))) unsigned short As[3][BM * BK];
    __shared__ __attribute__((aligned(16))) unsigned short Bs[3][BN * BK];

    const int z = blockIdx.z;
    const unsigned short* __restrict__ A  = a.A[z];
    const unsigned short* __restrict__ Bt = a.Bt[z];
    void* __restrict__ out = a.out[z];

    const int tid  = threadIdx.x;
    const int lane = tid & 63;
    const int wave = tid >> 6;
    const int m0 = blockIdx.x * BM;
    const int n0 = blockIdx.y * BN;

    const bool isA = (wave < 2);
    const int rowbase = (wave & 1) * 64;
    const unsigned short* gsrc = isA ? A : Bt;
    const int r   = lane >> 2;
    const int cb  = lane & 3;
    const int cbs = cb ^ ((r >> 1) & 3);
    const long grow0 = (isA ? (long)m0 : (long)n0) + rowbase;
    const unsigned short* gbase0 = gsrc + grow0 * KK + cbs * 8;
    unsigned short* lb[3] = {
        (isA ? As[0] : Bs[0]) + rowbase * BK,
        (isA ? As[1] : Bs[1]) + rowbase * BK,
        (isA ? As[2] : Bs[2]) + rowbase * BK };

    const int frow = lane & 15;
    const int fk   = ((lane >> 4) ^ ((frow >> 1) & 3)) * 8;
    const int wrow = wave >> 1;
    const int wcol = wave & 1;

    f32x4 acc[4][4] = {};

    stage4(gbase0 + 0 * BK, lb[0], r);
    stage4(gbase0 + 1 * BK, lb[1], r);
    stage4(gbase0 + 2 * BK, lb[2], r);

    #pragma unroll
    for (int ks = 0; ks < NT; ++ks) {
        if      (ks < NT - 2)  asm volatile("s_waitcnt vmcnt(8)" ::: "memory");
        else if (ks == NT - 2) asm volatile("s_waitcnt vmcnt(4)" ::: "memory");
        else                   asm volatile("s_waitcnt vmcnt(0)" ::: "memory");
        __builtin_amdgcn_s_barrier();
        asm volatile("" ::: "memory");

        const unsigned short* Asc = As[ks % 3];
        const unsigned short* Bsc = Bs[ks % 3];
        bf16x8 afr[4], bfr[4];
        #pragma unroll
        for (int i = 0; i < 4; ++i)
            afr[i] = *(const bf16x8*)(Asc + (wrow * 64 + i * 16 + frow) * BK + fk);
        #pragma unroll
        for (int j = 0; j < 4; ++j)
            bfr[j] = *(const bf16x8*)(Bsc + (wcol * 64 + j * 16 + frow) * BK + fk);

        #pragma unroll
        for (int i = 0; i < 4; ++i)
            #pragma unroll
            for (int j = 0; j < 4; ++j)
                acc[i][j] = __builtin_amdgcn_mfma_f32_16x16x32_bf16(
                    bfr[j], afr[i], acc[i][j], 0, 0, 0);

        asm volatile("" ::: "memory");
        __builtin_amdgcn_s_barrier();
        asm volatile("" ::: "memory");
        if (ks + 3 < NT)
            stage4(gbase0 + (ks + 3) * BK, lb[ks % 3], r);
    }

    const int mr  = lane & 15;
    const int cq4 = (lane >> 4) * 4;
    #pragma unroll
    for (int j = 0; j < 4; ++j) {
        const int col = n0 + wcol * 64 + j * 16 + cq4;
        #pragma unroll
        for (int i = 0; i < 4; ++i) {
            const long row = m0 + wrow * 64 + i * 16 + mr;
            f32x4 v = acc[i][j];
            u16x4 o;
            o[0] = f2bf(v[0]); o[1] = f2bf(v[1]);
            o[2] = f2bf(v[2]); o[3] = f2bf(v[3]);
            *(u16x4*)((unsigned short*)out + row * NN + col) = o;
        }
    }
}

// ---------------------------------------------------------------------------
// FUSED MLP: per block (z, m-tile of 128 rows):
//   for 4 chunks c (128 h-cols each):
//     G1: acc1 = fsum[mtile] @ WcT_z[c-rows]^T   (operands direct global->reg)
//     relu(+bcomb) -> bf16 -> h-chunk in LDS (XOR-swizzled, 32 KB)
//     G2: acc2 += h-chunk @ W2T_z[:, c-krange]^T (h from LDS, W2T global->reg)
//   epilogue: sigmoid(acc2 + b2) * fea -> out (fp32)
// h never touches HBM. 8 waves (2m x 4n). acc2 = 128 VGPR/lane.
// Global b128 fragment loads touch 16 fully-consumed 64B lines/instr.
// Barriers only around the h LDS hand-off (2 per chunk), lgkmcnt only --
// global prefetches stay in flight across them.
// ---------------------------------------------------------------------------
struct FArgs {
    const unsigned short* WcT[4];
    const unsigned short* W2T[4];
    const float* bcomb[4];
    const float* b2[4];
    const float* fea[4];
    float* out[4];
    const unsigned short* fsum;
};

__global__ __launch_bounds__(512, 2)
void fused_mlp(FArgs a)
{
    __shared__ __attribute__((aligned(16))) unsigned short hlds[128 * 128]; // 32 KB

    // chunked XCD decode: XCD k handles a contiguous band of m-tiles, all z.
    const int wg  = blockIdx.x;              // 0..1023
    const int gt  = (wg & 7) * 128 + (wg >> 3);
    const int z   = gt & 3;
    const int m0  = (gt >> 2) * 128;

    const int tid  = threadIdx.x;
    const int lane = tid & 63;
    const int wave = tid >> 6;
    const int wm = wave >> 2;      // 0..1 : m half (64 rows)
    const int wn = wave & 3;       // 0..3 : n quarter
    const int fr = lane & 15;      // fragment row
    const int fq = lane >> 4;      // 0..3 : k-seg (operands) / col-quad (C/D)

    const unsigned short* __restrict__ Afs = a.fsum;
    const unsigned short* __restrict__ Wc  = a.WcT[z];
    const unsigned short* __restrict__ W2  = a.W2T[z];
    const float* __restrict__ bc  = a.bcomb[z];
    const float* __restrict__ b2  = a.b2[z];
    const float* __restrict__ fea = a.fea[z];
    float* __restrict__ out = a.out[z];

    f32x4 acc2[4][8] = {};

    for (int c = 0; c < 4; ++c) {
        // ---- G1: h-chunk c (128 x 128), per wave 64x32 ----
        f32x4 acc1[4][2] = {};
        #pragma unroll 4
        for (int ks = 0; ks < 16; ++ks) {
            bf16x8 afr[4], bfr[2];
            #pragma unroll
            for (int mi = 0; mi < 4; ++mi)
                afr[mi] = *(const bf16x8*)(Afs +
                    (long)(m0 + wm * 64 + mi * 16 + fr) * 512 + ks * 32 + fq * 8);
            #pragma unroll
            for (int ni = 0; ni < 2; ++ni)
                bfr[ni] = *(const bf16x8*)(Wc +
                    (long)(c * 128 + wn * 32 + ni * 16 + fr) * 512 + ks * 32 + fq * 8);
            #pragma unroll
            for (int mi = 0; mi < 4; ++mi)
                #pragma unroll
                for (int ni = 0; ni < 2; ++ni)
                    acc1[mi][ni] = __builtin_amdgcn_mfma_f32_16x16x32_bf16(
                        bfr[ni], afr[mi], acc1[mi][ni], 0, 0, 0);
        }

        // protect previous chunk's G2 reads before overwriting h
        asm volatile("" ::: "memory");
        __builtin_amdgcn_s_barrier();
        asm volatile("" ::: "memory");

        // ---- bias + relu + bf16 -> h LDS (XOR swizzle: byte ^= (row&7)<<4) ----
        #pragma unroll
        for (int mi = 0; mi < 4; ++mi) {
            #pragma unroll
            for (int ni = 0; ni < 2; ++ni) {
                const int colh = wn * 32 + ni * 16 + fq * 4;   // chunk-local col
                const f32x4 bcv = *(const f32x4*)(bc + c * 128 + colh);
                const int row = wm * 64 + mi * 16 + fr;
                u16x4 o;
                #pragma unroll
                for (int q = 0; q < 4; ++q)
                    o[q] = f2bf(fmaxf(acc1[mi][ni][q] + bcv[q], 0.0f));
                const int byte = row * 256 + ((colh * 2) ^ ((row & 7) << 4));
                *(u16x4*)((char*)hlds + byte) = o;
            }
        }
        asm volatile("s_waitcnt lgkmcnt(0)" ::: "memory");
        __builtin_amdgcn_s_barrier();
        asm volatile("" ::: "memory");

        // ---- G2: acc2 += h-chunk @ W2T[:, c*128 ..], per wave 64x128 ----
        #pragma unroll
        for (int ks2 = 0; ks2 < 4; ++ks2) {
            bf16x8 hfr[4], b2fr[8];
            #pragma unroll
            for (int mi = 0; mi < 4; ++mi) {
                const int row = wm * 64 + mi * 16 + fr;
                const int byte = row * 256 + ((ks2 * 64 + fq * 16) ^ ((row & 7) << 4));
                hfr[mi] = *(const bf16x8*)((const char*)hlds + byte);
            }
            #pragma unroll
            for (int ni = 0; ni < 8; ++ni)
                b2fr[ni] = *(const bf16x8*)(W2 +
                    (long)(wn * 128 + ni * 16 + fr) * 512 + c * 128 + ks2 * 32 + fq * 8);
            #pragma unroll
            for (int mi = 0; mi < 4; ++mi)
                #pragma unroll
                for (int ni = 0; ni < 8; ++ni)
                    acc2[mi][ni] = __builtin_amdgcn_mfma_f32_16x16x32_bf16(
                        b2fr[ni], hfr[mi], acc2[mi][ni], 0, 0, 0);
        }
    }

    // ---- epilogue: sigmoid(acc2 + b2) * fea -> out ----
    #pragma unroll
    for (int ni = 0; ni < 8; ++ni) {
        const int col = wn * 128 + ni * 16 + fq * 4;
        const f32x4 bv = *(const f32x4*)(b2 + col);
        #pragma unroll
        for (int mi = 0; mi < 4; ++mi) {
            const long row = m0 + wm * 64 + mi * 16 + fr;
            f32x4 v = acc2[mi][ni] + bv;
            f32x4 fv = *(const f32x4*)(fea + row * 512 + col);
            f32x4 o;
            #pragma unroll
            for (int q = 0; q < 4; ++q) {
                const float e = __expf(-v[q]);
                o[q] = __fdividef(fv[q], 1.0f + e);
            }
            *(f32x4*)(out + row * 512 + col) = o;
        }
    }
}

// ---------------------------------------------------------------------------
extern "C" void kernel_launch(void* const* d_in, const int* in_sizes, int n_in,
                              void* d_out, int out_size, void* d_ws, size_t ws_size,
                              hipStream_t stream)
{
    (void)in_sizes; (void)n_in; (void)out_size; (void)ws_size;

    const float* fea[4] = {(const float*)d_in[0], (const float*)d_in[1],
                           (const float*)d_in[2], (const float*)d_in[3]};
    const float* W_gcn = (const float*)d_in[4];
    const float* b_gcn = (const float*)d_in[5];
    const float *W1[4], *b1[4], *W2[4], *b2[4];
    for (int i = 0; i < 4; ++i) {
        W1[i] = (const float*)d_in[6 + 4 * i];
        b1[i] = (const float*)d_in[7 + 4 * i];
        W2[i] = (const float*)d_in[8 + 4 * i];
        b2[i] = (const float*)d_in[9 + 4 * i];
    }

    // workspace layout (MiB offsets):
    //   [0,32)    fsum (bf16, 32768x512)
    //   [32,36.5) 9 bf16 weight mats: Wgb, W1T[0..3], W2T[0..3]  (512x512 each)
    //   [40,42)   WcombT[0..3] (bf16 512x512 each)
    //   [44,..)   bcomb (4 x 512 f32)
    const size_t MB = 1024 * 1024;
    char* ws = (char*)d_ws;
    unsigned short* fsum_h = (unsigned short*)ws;
    unsigned short* wbuf   = (unsigned short*)(ws + 32 * MB);
    unsigned short* Wgb = wbuf;
    unsigned short *W1T[4], *W2T[4], *WcT[4];
    for (int i = 0; i < 4; ++i) {
        W1T[i] = wbuf + (size_t)(1 + i) * 262144;
        W2T[i] = wbuf + (size_t)(5 + i) * 262144;
        WcT[i] = (unsigned short*)(ws + 40 * MB) + (size_t)i * 262144;
    }
    float* bcomb = (float*)(ws + 44 * MB);

    fsum_cast<<<8192, 256, 0, stream>>>(fea[0], fea[1], fea[2], fea[3], fsum_h);

    WArgs wa;
    wa.src[0] = W_gcn; wa.dst[0] = Wgb;
    for (int i = 0; i < 4; ++i) { wa.src[1 + i] = W1[i]; wa.dst[1 + i] = W1T[i]; }
    for (int i = 0; i < 4; ++i) { wa.src[5 + i] = W2[i]; wa.dst[5 + i] = W2T[i]; }
    wprep<<<dim3(16, 16, 9), dim3(32, 8), 0, stream>>>(wa);

    BArgs ba;
    for (int i = 0; i < 4; ++i) { ba.w1t[i] = W1T[i]; ba.b1[i] = b1[i]; ba.out[i] = bcomb + (size_t)i * 512; }
    bprep<<<4, 256, 0, stream>>>(b_gcn, ba);

    // WcombT_z[n][k] = sum_t W1T_z[n][t] * (0.25*Wg[k][t])
    GArgs g3;
    for (int i = 0; i < 4; ++i) {
        g3.A[i] = W1T[i]; g3.Bt[i] = Wgb; g3.bias[i] = nullptr;
        g3.fea[i] = nullptr; g3.out[i] = WcT[i];
    }
    gemm_ep<3><<<dim3(4, 4, 4), 256, 0, stream>>>(g3);

    // fused h + out stage
    FArgs fa;
    for (int i = 0; i < 4; ++i) {
        fa.WcT[i] = WcT[i]; fa.W2T[i] = W2T[i];
        fa.bcomb[i] = bcomb + (size_t)i * 512; fa.b2[i] = b2[i];
        fa.fea[i] = fea[i]; fa.out[i] = (float*)d_out + (size_t)i * MM * NN;
    }
    fa.fsum = fsum_h;
    fused_mlp<<<1024, 512, 0, stream>>>(fa);
}

// Round 5
// 810.701 us; speedup vs baseline: 1.3383x; 1.3383x over previous
//
#include <hip/hip_runtime.h>
#include <math.h>

// Problem constants: B=64, D=512, H=HID=512 -> M = B*D = 32768, K = N = 512.
#define MM 32768
#define KK 512
#define NN 512
#define BM 128
#define BN 128
#define BK 32
#define NT (KK / BK)   // 16 K-tiles

typedef float  f32x4  __attribute__((ext_vector_type(4)));
typedef __bf16 bf16x8 __attribute__((ext_vector_type(8)));
typedef unsigned short u16x8 __attribute__((ext_vector_type(8)));
typedef unsigned short u16x4 __attribute__((ext_vector_type(4)));

__device__ __forceinline__ unsigned short f2bf(float f) {
    union { float f; unsigned int u; } v; v.f = f;
    unsigned int r = v.u + 0x7fffu + ((v.u >> 16) & 1u);  // round-to-nearest-even
    return (unsigned short)(r >> 16);
}

__device__ __forceinline__ float bf2f(unsigned short h) {
    union { unsigned int u; float f; } v; v.u = ((unsigned int)h) << 16;
    return v.f;
}

__device__ __forceinline__ void gl_lds16(const void* g, void* l) {
    __builtin_amdgcn_global_load_lds((const __attribute__((address_space(1))) void*)g,
                                     (__attribute__((address_space(3))) void*)l,
                                     16, 0, 0);
}

// ---------------------------------------------------------------------------
// fsum = fea1+fea2+fea3+fea4, cast to bf16.  8 elements / thread.
// ---------------------------------------------------------------------------
__global__ __launch_bounds__(256)
void fsum_cast(const float* __restrict__ f1, const float* __restrict__ f2,
               const float* __restrict__ f3, const float* __restrict__ f4,
               unsigned short* __restrict__ out)
{
    const long i = ((long)blockIdx.x * 256 + threadIdx.x) * 8;
    f32x4 s0 = *(const f32x4*)(f1 + i);
    f32x4 s1 = *(const f32x4*)(f1 + i + 4);
    s0 += *(const f32x4*)(f2 + i);  s1 += *(const f32x4*)(f2 + i + 4);
    s0 += *(const f32x4*)(f3 + i);  s1 += *(const f32x4*)(f3 + i + 4);
    s0 += *(const f32x4*)(f4 + i);  s1 += *(const f32x4*)(f4 + i + 4);
    u16x8 o;
    o[0] = f2bf(s0[0]); o[1] = f2bf(s0[1]); o[2] = f2bf(s0[2]); o[3] = f2bf(s0[3]);
    o[4] = f2bf(s1[0]); o[5] = f2bf(s1[1]); o[6] = f2bf(s1[2]); o[7] = f2bf(s1[3]);
    *(u16x8*)(out + i) = o;
}

// ---------------------------------------------------------------------------
// Weight prep:
//   z = 0     : Wgb[k][t]   = 0.25 * W_gcn[k][t]          (bf16 cast, NO transpose)
//   z = 1..4  : W1T[n][t]   = sum_b W1_i[b*512 + t][n]    (transpose + concat collapse)
//   z = 5..8  : W2T[n][k]   = W2_i[k][n]                  (transpose)
// ---------------------------------------------------------------------------
struct WArgs {
    const float* src[9];
    unsigned short* dst[9];
};

__global__ __launch_bounds__(256)
void wprep(WArgs a)
{
    __shared__ float t[32][33];
    const int z  = blockIdx.z;
    const float* __restrict__ src = a.src[z];
    unsigned short* __restrict__ dst = a.dst[z];
    const int k0 = blockIdx.x * 32;
    const int n0 = blockIdx.y * 32;
    const int tx = threadIdx.x;
    if (z == 0) {
        for (int kk = threadIdx.y; kk < 32; kk += 8) {
            float v = src[(long)(k0 + kk) * 512 + n0 + tx];
            dst[(long)(k0 + kk) * 512 + n0 + tx] = f2bf(0.25f * v);
        }
        return;
    }
    for (int kk = threadIdx.y; kk < 32; kk += 8) {
        float v = src[(long)(k0 + kk) * 512 + n0 + tx];
        if (z >= 1 && z <= 4) {
            v += src[(long)(512  + k0 + kk) * 512 + n0 + tx];
            v += src[(long)(1024 + k0 + kk) * 512 + n0 + tx];
            v += src[(long)(1536 + k0 + kk) * 512 + n0 + tx];
        }
        t[kk][tx] = v;
    }
    __syncthreads();
    for (int nn = threadIdx.y; nn < 32; nn += 8) {
        dst[(long)(n0 + nn) * 512 + k0 + tx] = f2bf(t[tx][nn]);
    }
}

// ---------------------------------------------------------------------------
// bcomb_z[n] = sum_t b_gcn[t] * W1T_z[n][t] + b1_z[n]
// ---------------------------------------------------------------------------
struct BArgs {
    const unsigned short* w1t[4];
    const float* b1[4];
    float* out[4];
};

__global__ __launch_bounds__(256)
void bprep(const float* __restrict__ bg, BArgs a)
{
    __shared__ float bgs[512];
    const int z = blockIdx.x;
    const int tid = threadIdx.x;
    bgs[tid]       = bg[tid];
    bgs[tid + 256] = bg[tid + 256];
    __syncthreads();
    const unsigned short* __restrict__ w = a.w1t[z];
    for (int n = tid; n < 512; n += 256) {
        float acc = 0.0f;
        const unsigned short* row = w + (long)n * 512;
        #pragma unroll 4
        for (int t = 0; t < 512; t += 8) {
            u16x8 wv = *(const u16x8*)(row + t);
            #pragma unroll
            for (int jj = 0; jj < 8; ++jj) acc += bgs[t + jj] * bf2f(wv[jj]);
        }
        a.out[z][n] = acc + a.b1[z][n];
    }
}

// ---------------------------------------------------------------------------
// GEMM: C(M x N) = A(M x K, bf16) @ Bt(N x K, bf16)^T, + epilogue.
// MODE 1: store bf16(relu(v + bias))         (h stage)
// MODE 2: store fp32 sigmoid(v + bias)*fea   (output stage)
// MODE 3: store bf16(v), no bias             (composed-weight stage, 3D grid)
//
// Core (verified r2): 128x128 tile, BK=32, 4 waves, 3-deep counted-vmcnt LDS
// pipeline, K-seg XOR swizzle (0 bank conflicts), swapped-operand MFMA ->
// vectorized epilogue.
//
// r4/r5: modes 1/2 use a FLAT grid (4096) with an XCD-locality remap:
//   xcd = id & 7, rank = id >> 3, bx = xcd + 8*(rank>>4), (by,z) = rank & 15.
// All 16 blocks sharing an A m-tile become temporally adjacent on ONE XCD
// (~768 KB of A-tiles + ~2 MB weights co-resident in its 4 MB L2), so the
// A-tile is fetched once and served 15x from L2 instead of 16x from L3/HBM.
// Bijective: 8 xcd x 32 (rank>>4) -> bx covers 0..255 once per (by,z);
// rank&15 -> 16 (by,z) pairs; 8*512 = 256*16 = 4096.
// ---------------------------------------------------------------------------
struct GArgs {
    const unsigned short* A[4];
    const unsigned short* Bt[4];
    const float* bias[4];
    const float* fea[4];
    void* out[4];
};

__device__ __forceinline__ void stage4(const unsigned short* gb, unsigned short* lb, int r) {
    #pragma unroll
    for (int c = 0; c < 4; ++c)
        gl_lds16(gb + (long)(c * 16 + r) * KK, lb + c * 16 * BK);
}

template<int MODE>
__global__ __launch_bounds__(256)
void gemm_ep(GArgs a)
{
    __shared__ __attribute__((aligned(16))) unsigned short As[3][BM * BK];  // 3 x 8 KB
    __shared__ __attribute__((aligned(16))) unsigned short Bs[3][BN * BK];  // 3 x 8 KB

    int bx, by, z;
    if (MODE == 3) {
        bx = blockIdx.x; by = blockIdx.y; z = blockIdx.z;
    } else {
        const int id   = blockIdx.x;      // 0..4095
        const int xcd  = id & 7;
        const int rank = id >> 3;         // 0..511
        bx = xcd + 8 * (rank >> 4);       // A m-tile: 16 consecutive ranks share it
        by = rank & 3;
        z  = (rank >> 2) & 3;
    }

    const unsigned short* __restrict__ A  = a.A[z];
    const unsigned short* __restrict__ Bt = a.Bt[z];
    const float* __restrict__ bias = a.bias[z];
    const float* __restrict__ fea  = a.fea[z];
    void* __restrict__ out = a.out[z];

    const int tid  = threadIdx.x;
    const int lane = tid & 63;
    const int wave = tid >> 6;
    const int m0 = bx * BM;
    const int n0 = by * BN;

    // staging role (wave-uniform): waves 0/1 stage A rows 0-63/64-127, waves 2/3 Bt.
    const bool isA = (wave < 2);
    const int rowbase = (wave & 1) * 64;
    const unsigned short* gsrc = isA ? A : Bt;
    const int r   = lane >> 2;                  // 0..15 : row within 16-row chunk
    const int cb  = lane & 3;                   // 0..3  : 16B segment within 64B row
    const int cbs = cb ^ ((r >> 1) & 3);        // pre-swizzled global segment
    const long grow0 = (isA ? (long)m0 : (long)n0) + rowbase;
    const unsigned short* gbase0 = gsrc + grow0 * KK + cbs * 8;
    unsigned short* lb[3] = {
        (isA ? As[0] : Bs[0]) + rowbase * BK,
        (isA ? As[1] : Bs[1]) + rowbase * BK,
        (isA ? As[2] : Bs[2]) + rowbase * BK };

    // fragment geometry: frag[idx = lane&15][k-seg = (lane>>4) ^ swz(frow)]
    const int frow = lane & 15;
    const int fk   = ((lane >> 4) ^ ((frow >> 1) & 3)) * 8;   // un-swizzled read
    const int wrow = wave >> 1;
    const int wcol = wave & 1;

    f32x4 acc[4][4] = {};

    // prologue: fill the 3-deep pipe (12 loads in flight per lane)
    stage4(gbase0 + 0 * BK, lb[0], r);
    stage4(gbase0 + 1 * BK, lb[1], r);
    stage4(gbase0 + 2 * BK, lb[2], r);

    #pragma unroll
    for (int ks = 0; ks < NT; ++ks) {
        if      (ks < NT - 2)  asm volatile("s_waitcnt vmcnt(8)" ::: "memory");
        else if (ks == NT - 2) asm volatile("s_waitcnt vmcnt(4)" ::: "memory");
        else                   asm volatile("s_waitcnt vmcnt(0)" ::: "memory");
        __builtin_amdgcn_s_barrier();            // everyone's tile-ks loads landed
        asm volatile("" ::: "memory");

        const unsigned short* Asc = As[ks % 3];
        const unsigned short* Bsc = Bs[ks % 3];
        bf16x8 afr[4], bfr[4];
        #pragma unroll
        for (int i = 0; i < 4; ++i)
            afr[i] = *(const bf16x8*)(Asc + (wrow * 64 + i * 16 + frow) * BK + fk);
        #pragma unroll
        for (int j = 0; j < 4; ++j)
            bfr[j] = *(const bf16x8*)(Bsc + (wcol * 64 + j * 16 + frow) * BK + fk);

        #pragma unroll
        for (int i = 0; i < 4; ++i)
            #pragma unroll
            for (int j = 0; j < 4; ++j)
                acc[i][j] = __builtin_amdgcn_mfma_f32_16x16x32_bf16(
                    bfr[j], afr[i], acc[i][j], 0, 0, 0);   // swapped operands

        asm volatile("" ::: "memory");
        __builtin_amdgcn_s_barrier();            // everyone done reading buf[ks%3]
        asm volatile("" ::: "memory");
        if (ks + 3 < NT)
            stage4(gbase0 + (ks + 3) * BK, lb[ks % 3], r);  // refill freed buffer
    }

    // epilogue: swapped C/D layout -> row = lane&15, cols = (lane>>4)*4 + 0..3
    const int mr  = lane & 15;
    const int cq4 = (lane >> 4) * 4;
    #pragma unroll
    for (int j = 0; j < 4; ++j) {
        const int col = n0 + wcol * 64 + j * 16 + cq4;
        f32x4 bv;
        if (MODE == 3) { bv[0] = bv[1] = bv[2] = bv[3] = 0.0f; }
        else           { bv = *(const f32x4*)(bias + col); }
        #pragma unroll
        for (int i = 0; i < 4; ++i) {
            const long row = m0 + wrow * 64 + i * 16 + mr;
            f32x4 v = acc[i][j] + bv;
            if (MODE == 1) {
                u16x4 o;
                o[0] = f2bf(fmaxf(v[0], 0.0f)); o[1] = f2bf(fmaxf(v[1], 0.0f));
                o[2] = f2bf(fmaxf(v[2], 0.0f)); o[3] = f2bf(fmaxf(v[3], 0.0f));
                *(u16x4*)((unsigned short*)out + row * NN + col) = o;
            } else if (MODE == 3) {
                u16x4 o;
                o[0] = f2bf(v[0]); o[1] = f2bf(v[1]);
                o[2] = f2bf(v[2]); o[3] = f2bf(v[3]);
                *(u16x4*)((unsigned short*)out + row * NN + col) = o;
            } else {  // MODE 2: sigmoid gate * fea, fp32 out
                f32x4 fv = *(const f32x4*)(fea + row * NN + col);
                f32x4 o;
                #pragma unroll
                for (int q = 0; q < 4; ++q) {
                    float e = __expf(-v[q]);
                    o[q] = __fdividef(fv[q], 1.0f + e);
                }
                *(f32x4*)((float*)out + row * NN + col) = o;
            }
        }
    }
}

// ---------------------------------------------------------------------------
extern "C" void kernel_launch(void* const* d_in, const int* in_sizes, int n_in,
                              void* d_out, int out_size, void* d_ws, size_t ws_size,
                              hipStream_t stream)
{
    (void)in_sizes; (void)n_in; (void)out_size; (void)ws_size;

    const float* fea[4] = {(const float*)d_in[0], (const float*)d_in[1],
                           (const float*)d_in[2], (const float*)d_in[3]};
    const float* W_gcn = (const float*)d_in[4];
    const float* b_gcn = (const float*)d_in[5];
    const float *W1[4], *b1[4], *W2[4], *b2[4];
    for (int i = 0; i < 4; ++i) {
        W1[i] = (const float*)d_in[6 + 4 * i];
        b1[i] = (const float*)d_in[7 + 4 * i];
        W2[i] = (const float*)d_in[8 + 4 * i];
        b2[i] = (const float*)d_in[9 + 4 * i];
    }

    // workspace layout (MiB offsets):
    //   [0,32)    fsum (bf16, 32768x512)
    //   [32,36.5) 9 bf16 weight mats: Wgb, W1T[0..3], W2T[0..3]  (512x512 each)
    //   [40,42)   WcombT[0..3] (bf16 512x512 each)
    //   [44,..)   bcomb (4 x 512 f32)
    //   [48,176)  h[0..3] (bf16 32768x512 each, 32 MiB apart)
    const size_t MB = 1024 * 1024;
    char* ws = (char*)d_ws;
    unsigned short* fsum_h = (unsigned short*)ws;
    unsigned short* wbuf   = (unsigned short*)(ws + 32 * MB);
    unsigned short* Wgb = wbuf;
    unsigned short *W1T[4], *W2T[4], *WcT[4], *hbuf[4];
    for (int i = 0; i < 4; ++i) {
        W1T[i] = wbuf + (size_t)(1 + i) * 262144;
        W2T[i] = wbuf + (size_t)(5 + i) * 262144;
        WcT[i] = (unsigned short*)(ws + 40 * MB) + (size_t)i * 262144;
        hbuf[i] = (unsigned short*)(ws + 48 * MB + (size_t)i * 32 * MB);
    }
    float* bcomb = (float*)(ws + 44 * MB);

    fsum_cast<<<8192, 256, 0, stream>>>(fea[0], fea[1], fea[2], fea[3], fsum_h);

    WArgs wa;
    wa.src[0] = W_gcn; wa.dst[0] = Wgb;
    for (int i = 0; i < 4; ++i) { wa.src[1 + i] = W1[i]; wa.dst[1 + i] = W1T[i]; }
    for (int i = 0; i < 4; ++i) { wa.src[5 + i] = W2[i]; wa.dst[5 + i] = W2T[i]; }
    wprep<<<dim3(16, 16, 9), dim3(32, 8), 0, stream>>>(wa);

    BArgs ba;
    for (int i = 0; i < 4; ++i) { ba.w1t[i] = W1T[i]; ba.b1[i] = b1[i]; ba.out[i] = bcomb + (size_t)i * 512; }
    bprep<<<4, 256, 0, stream>>>(b_gcn, ba);

    // WcombT_z[n][k] = sum_t W1T_z[n][t] * (0.25*Wg[k][t])   (512x512x512)
    GArgs g3;
    for (int i = 0; i < 4; ++i) {
        g3.A[i] = W1T[i]; g3.Bt[i] = Wgb; g3.bias[i] = nullptr;
        g3.fea[i] = nullptr; g3.out[i] = WcT[i];
    }
    gemm_ep<3><<<dim3(4, 4, 4), 256, 0, stream>>>(g3);

    // h_z = relu(fsum @ WcombT_z^T + bcomb_z)   -- flat grid + XCD remap
    GArgs g1;
    for (int i = 0; i < 4; ++i) {
        g1.A[i] = fsum_h; g1.Bt[i] = WcT[i]; g1.bias[i] = bcomb + (size_t)i * 512;
        g1.fea[i] = nullptr; g1.out[i] = hbuf[i];
    }
    gemm_ep<1><<<4096, 256, 0, stream>>>(g1);

    // out_z = sigmoid(h_z @ W2T_z^T + b2_z) * fea_z   -- flat grid + XCD remap
    float* outp = (float*)d_out;
    GArgs g2;
    for (int i = 0; i < 4; ++i) {
        g2.A[i] = hbuf[i]; g2.Bt[i] = W2T[i]; g2.bias[i] = b2[i];
        g2.fea[i] = fea[i]; g2.out[i] = outp + (size_t)i * MM * NN;
    }
    gemm_ep<2><<<4096, 256, 0, stream>>>(g2);
}